// Round 11
// baseline (4833.652 us; speedup 1.0000x reference)
//
#include <hip/hip_runtime.h>
#include <math.h>

namespace {

constexpr int Bb = 1024;
constexpr int Tn = 64;
constexpr int Dn = 8;
constexpr int Hn = 64;
constexpr int Wn = 128;
constexpr int BT = 4;     // batch rows per block
constexpr int NT = 1024;  // 16 waves, 4 waves/SIMD, 1 block/CU
constexpr int W1S = 68;   // w1s row stride
constexpr int W2S = 132;  // w2s row stride
constexpr int YS  = 72;   // y/ys row stride: rows 8 banks apart
constexpr int HS  = 136;  // h1 row stride; halves at phys 0 / 68 (gap)
constexpr int GAP = 68;   // phys offset of h1's k=64..127 half
constexpr int KS  = 68;   // K_l inner stride
constexpr int Q2S = 132;  // h2q row stride in float2 units (gap at k=64: +2)

typedef float v2f __attribute__((ext_vector_type(2)));

// Tsit5 tableau
constexpr float A21 = 0.161f;
constexpr float A31 = -0.008480655492356989f, A32 = 0.335480655492357f;
constexpr float A41 = 2.8971530571054935f, A42 = -6.359448489975075f, A43 = 4.3622954328695815f;
constexpr float A51 = 5.325864828439257f, A52 = -11.748883564062828f, A53 = 7.4955393428898365f, A54 = -0.09249506636175525f;
constexpr float A61 = 5.86145544294642f, A62 = -12.92096931784711f, A63 = 8.159367898576159f, A64 = -0.071584973281401f, A65 = -0.028269050394068383f;
constexpr float Bc1 = 0.09646076681806523f, Bc2 = 0.01f, Bc3 = 0.4798896504144996f;
constexpr float Bc4 = 1.379008574103742f, Bc5 = -3.290069515436081f, Bc6 = 2.324710524099774f;

// fast transcendentals (v_exp/v_log/v_rcp based)
__device__ inline float fast_softplus(float x) {
  const float e = __expf(-fabsf(x));           // e in (0,1]
  return fmaxf(x, 0.f) + __logf(1.f + e);      // 1+e in [1,2]
}
__device__ inline float fast_tanh(float x) {
  const float xc = fminf(fmaxf(x, -10.f), 10.f);
  const float e2 = __expf(2.f * xc);
  return 1.f - __fdividef(2.f, e2 + 1.f);
}
__device__ inline float fast_sigmoid(float z) {
  return __fdividef(1.f, 1.f + __expf(-z));
}
__device__ inline float dot4(float4 w, float4 a) {
  return w.x * a.x + w.y * a.y + w.z * a.z + w.w * a.w;
}
// packed dual-FMA accumulate (v_pk_fma_f32)
__device__ inline v2f pkfma(v2f a, v2f b, v2f acc) {
  return __builtin_elementwise_fma(a, b, acc);
}

} // namespace

// Persistent per-batch-tile NeuralCDE integrator, 1024 threads/block.
//
// R11 = R9 (2043us, zero-conflict, no-spill) + pk_fma on L3 with the R10
// spill mechanism fixed:
//  * R10's flat 64-read L3 loop let LLVM hoist unbounded ds_read_b128s
//    (256 temp VGPRs) -> w3r[64] demoted to scratch (FETCH 11GB, 4.3ms).
//    R11 bounds in-flight loads with sched_barrier(0) every 8 reads.
//  * h2 pair-interleaved: h2q[pair][k'] float2 = {h2[2p][k], h2[2p+1][k]},
//    k' = k + (k>=64 ? 2 : 0) -> the two hf wave-addresses land on
//    disjoint bank quads (zero-conflict preserved). One b128 read = 2 k's
//    x 2 batches: still 64 reads/thread/stage, but 128 pk_fma vs 256 FMA.
//  * L1/L2 (half-thread scalar form), w3r regs, fused update: R9 verbatim.
// Tripwire: FETCH_SIZE >= 1e5 KB => spill returned.
__global__ __launch_bounds__(NT, 4)
void ncde_kernel(const float* __restrict__ xs,
                 const float* __restrict__ iw1, const float* __restrict__ ib1,
                 const float* __restrict__ iw2, const float* __restrict__ ib2,
                 const float* __restrict__ iw3, const float* __restrict__ ib3,
                 const float* __restrict__ vw1, const float* __restrict__ vb1,
                 const float* __restrict__ vw2, const float* __restrict__ vb2,
                 const float* __restrict__ vw3, const float* __restrict__ vb3,
                 const float* __restrict__ lw,  const float* __restrict__ lb,
                 float* __restrict__ out)
{
  __shared__ float w1s[Wn][W1S];          // 34.8 KB: w1s[o][k] row-major
  __shared__ float w2s[Wn][W2S];          // 67.6 KB: w2s[o][k] row-major
  __shared__ float xs_l[BT][Tn * Dn];     // 8 KB control path
  __shared__ float y_l[BT][YS];           // current state
  __shared__ float ys_l[BT][YS];          // stage input
  __shared__ float K_l[6][BT][KS];        // stage slopes
  __shared__ float h1_l[BT][HS];          // gap layout: [0..63] + [68..131]
  __shared__ v2f   h2q[2][Q2S];           // pair-interleaved h2 (2.1 KB)
  __shared__ float lw_l[Hn];

  const int tid = threadIdx.x;
  const int b12 = tid & 3;          // L1/L2 batch row (tid<512)
  const int oL  = (tid >> 2) & 127; // L1/L2 output neuron (tid<512)
  const int pOL = oL + (oL >= 64 ? 4 : 0);   // gap phys index into h1
  // h2q write slot (float index): pair*2*Q2S + k'*2 + (b&1)
  const int h2w = (b12 >> 1) * 2 * Q2S + (oL + (oL >= 64 ? 2 : 0)) * 2 + (b12 & 1);
  const int hf  = tid & 1;          // L3 k-half
  const int d   = (tid >> 1) & 7;   // L3 data-dim (vw3 row = tid>>1 = h3*8+d)
  const int h3  = tid >> 4;         // L3 hidden index, 0..63
  const int b0  = blockIdx.x * BT;
  float* const h2qf = (float*)&h2q[0][0];

  const float b1r = vb1[oL];
  const float b2r = vb2[oL];
  const float b3r = vb3[tid >> 1];
  const float lb0 = lb[0];

  // ---- w3 half-row -> registers, ONCE (contiguous 256B per lane) ----
  float w3r[64];
  {
    const float4* p = (const float4*)(vw3 + tid * 64);  // (tid>>1)*128+(tid&1)*64
    #pragma unroll
    for (int i = 0; i < 16; ++i) {
      float4 v = p[i];
      w3r[4*i+0] = v.x; w3r[4*i+1] = v.y; w3r[4*i+2] = v.z; w3r[4*i+3] = v.w;
    }
  }

  // ---- stage w1/w2 row-major into LDS ----
  #pragma unroll
  for (int i = 0; i < 8; ++i) {           // 8192 f32 / 1024 threads
    const int e = i * NT + tid;           // e = o*64 + k
    w1s[e >> 6][e & 63] = vw1[e];
  }
  #pragma unroll
  for (int i = 0; i < 16; ++i) {          // 16384 f32 / 1024 threads
    const int e = i * NT + tid;           // e = o*128 + k
    w2s[e >> 7][e & 127] = vw2[e];
  }
  // ---- this block's xs rows (512 x float4 = 8 KB) ----
  if (tid < 512)
    ((float4*)&xs_l[0][0])[tid] = ((const float4*)(xs + b0 * Tn * Dn))[tid];
  if (tid < Hn) lw_l[tid] = lw[tid];
  __syncthreads();

  // ---- initial MLP (relu, relu, identity): y0 = mlp(xs[:,0]) ----
  if (tid < 512) {
    const int b = tid >> 7, oo = tid & 127;
    float acc = ib1[oo];
    #pragma unroll
    for (int k = 0; k < Dn; ++k) acc += iw1[oo * Dn + k] * xs_l[b][k];
    h1_l[b][oo + (oo >= 64 ? 4 : 0)] = fmaxf(acc, 0.f);
  }
  __syncthreads();
  if (tid < 512) {
    const int b = tid >> 7, oo = tid & 127;
    float acc = ib2[oo];
    const float4* wrow = (const float4*)(iw2 + oo * Wn);
    #pragma unroll
    for (int k4 = 0; k4 < 16; ++k4)
      acc += dot4(wrow[k4], *(const float4*)&h1_l[b][k4 * 4]);
    #pragma unroll
    for (int k4 = 0; k4 < 16; ++k4)
      acc += dot4(wrow[16 + k4], *(const float4*)&h1_l[b][GAP + k4 * 4]);
    h2qf[(b >> 1) * 2 * Q2S + (oo + (oo >= 64 ? 2 : 0)) * 2 + (b & 1)] =
        fmaxf(acc, 0.f);
  }
  __syncthreads();
  if (tid < BT * Hn) {
    const int b = tid >> 6, h = tid & (Hn - 1);
    float acc = ib3[h];
    for (int k = 0; k < Wn; ++k)
      acc += iw3[h * Wn + k] *
             h2qf[(b >> 1) * 2 * Q2S + (k + (k >= 64 ? 2 : 0)) * 2 + (b & 1)];
    y_l[b][h]  = acc;
    ys_l[b][h] = acc;
  }
  __syncthreads();

  auto readout = [&](int t) {
    if (tid < BT * Hn) {
      const int wv = tid >> 6, h = tid & (Hn - 1);
      float p = lw_l[h] * y_l[wv][h];
      #pragma unroll
      for (int off = 32; off > 0; off >>= 1) p += __shfl_xor(p, off, 64);
      if (h == 0) out[(b0 + wv) * Tn + t] = fast_sigmoid(p + lb0);
    }
  };
  readout(0);

  // ---- 63 Tsit5 steps; per stage: L1 -> bar -> L2 -> bar -> L3+update -> bar
  #pragma unroll 1
  for (int t = 0; t < Tn - 1; ++t) {
    float dxr[BT];

    #pragma unroll 1
    for (int s = 0; s < 6; ++s) {
      if (s == 0) {
        #pragma unroll
        for (int b = 0; b < BT; ++b)
          dxr[b] = xs_l[b][(t + 1) * Dn + d] - xs_l[b][t * Dn + d];
      }

      // ---- vf layer 1 (tid<512): full 64-k dot, gap-mapped write ----
      if (tid < 512) {
        float acc = b1r;
        #pragma unroll
        for (int k4 = 0; k4 < 16; ++k4)
          acc += dot4(*(const float4*)&w1s[oL][k4 * 4],
                      *(const float4*)&ys_l[b12][k4 * 4]);
        h1_l[b12][pOL] = fast_softplus(acc);
      }
      __syncthreads();
      // ---- vf layer 2 (tid<512): full 128-k dot, pair-interleaved write ----
      if (tid < 512) {
        float acc = b2r;
        #pragma unroll
        for (int k4 = 0; k4 < 16; ++k4)
          acc += dot4(*(const float4*)&w2s[oL][k4 * 4],
                      *(const float4*)&h1_l[b12][k4 * 4]);
        #pragma unroll
        for (int k4 = 0; k4 < 16; ++k4)
          acc += dot4(*(const float4*)&w2s[oL][64 + k4 * 4],
                      *(const float4*)&h1_l[b12][GAP + k4 * 4]);
        h2qf[h2w] = fast_softplus(acc);
      }
      __syncthreads();
      // ---- vf layer 3 (all 1024): pk_fma batch-pairs, bounded in-flight
      //      loads (sched_barrier every 8 reads), fused update ----
      {
        v2f Ap0 = {0.f, 0.f}, Ap1 = {0.f, 0.f};
        const int kb2 = hf ? 66 : 0;        // float2-unit base of my k-half
        const float4* q0 = (const float4*)&h2q[0][kb2];
        const float4* q1 = (const float4*)&h2q[1][kb2];
        #pragma unroll
        for (int cc = 0; cc < 8; ++cc) {
          #pragma unroll
          for (int j = 0; j < 4; ++j) {
            const int c = cc * 4 + j;       // covers k = 2c, 2c+1
            const float4 a4 = q0[c];
            const float4 b4 = q1[c];
            const v2f* ap = (const v2f*)&a4;
            const v2f* bp = (const v2f*)&b4;
            const v2f w0 = {w3r[2*c],     w3r[2*c]};
            const v2f w1 = {w3r[2*c + 1], w3r[2*c + 1]};
            Ap0 = pkfma(w0, ap[0], Ap0);
            Ap0 = pkfma(w1, ap[1], Ap0);
            Ap1 = pkfma(w0, bp[0], Ap1);
            Ap1 = pkfma(w1, bp[1], Ap1);
          }
          __builtin_amdgcn_sched_barrier(0);  // cap in-flight b128 loads
        }
        float a0 = Ap0.x, a1 = Ap0.y, a2 = Ap1.x, a3 = Ap1.y;
        // join k-halves (pair lane), tanh, einsum over d
        a0 += __shfl_xor(a0, 1, 64);
        a1 += __shfl_xor(a1, 1, 64);
        a2 += __shfl_xor(a2, 1, 64);
        a3 += __shfl_xor(a3, 1, 64);
        float p0 = fast_tanh(a0 + b3r) * dxr[0];
        float p1 = fast_tanh(a1 + b3r) * dxr[1];
        float p2 = fast_tanh(a2 + b3r) * dxr[2];
        float p3 = fast_tanh(a3 + b3r) * dxr[3];
        p0 += __shfl_xor(p0, 2, 64); p0 += __shfl_xor(p0, 4, 64); p0 += __shfl_xor(p0, 8, 64);
        p1 += __shfl_xor(p1, 2, 64); p1 += __shfl_xor(p1, 4, 64); p1 += __shfl_xor(p1, 8, 64);
        p2 += __shfl_xor(p2, 2, 64); p2 += __shfl_xor(p2, 4, 64); p2 += __shfl_xor(p2, 8, 64);
        p3 += __shfl_xor(p3, 2, 64); p3 += __shfl_xor(p3, 4, 64); p3 += __shfl_xor(p3, 8, 64);
        const int wl = tid & 15;
        if (wl < BT) {
          const float kv = (wl == 0) ? p0 : (wl == 1) ? p1 : (wl == 2) ? p2 : p3;
          K_l[s][wl][h3] = kv;
          float v = y_l[wl][h3];
          if (s == 0)      v += A21 * kv;
          else if (s == 1) v += A31 * K_l[0][wl][h3] + A32 * kv;
          else if (s == 2) v += A41 * K_l[0][wl][h3] + A42 * K_l[1][wl][h3] + A43 * kv;
          else if (s == 3) v += A51 * K_l[0][wl][h3] + A52 * K_l[1][wl][h3]
                              + A53 * K_l[2][wl][h3] + A54 * kv;
          else if (s == 4) v += A61 * K_l[0][wl][h3] + A62 * K_l[1][wl][h3]
                              + A63 * K_l[2][wl][h3] + A64 * K_l[3][wl][h3] + A65 * kv;
          else             v += Bc1 * K_l[0][wl][h3] + Bc2 * K_l[1][wl][h3]
                              + Bc3 * K_l[2][wl][h3] + Bc4 * K_l[3][wl][h3]
                              + Bc5 * K_l[4][wl][h3] + Bc6 * kv;
          if (s < 5) {
            ys_l[wl][h3] = v;
          } else {
            y_l[wl][h3]  = v;
            ys_l[wl][h3] = v;
          }
        }
      }
      __syncthreads();
    }
    readout(t + 1);
  }
}

extern "C" void kernel_launch(void* const* d_in, const int* in_sizes, int n_in,
                              void* d_out, int out_size, void* d_ws, size_t ws_size,
                              hipStream_t stream) {
  const float* xs  = (const float*)d_in[1];
  const float* iw1 = (const float*)d_in[2];
  const float* ib1 = (const float*)d_in[3];
  const float* iw2 = (const float*)d_in[4];
  const float* ib2 = (const float*)d_in[5];
  const float* iw3 = (const float*)d_in[6];
  const float* ib3 = (const float*)d_in[7];
  const float* vw1 = (const float*)d_in[8];
  const float* vb1 = (const float*)d_in[9];
  const float* vw2 = (const float*)d_in[10];
  const float* vb2 = (const float*)d_in[11];
  const float* vw3 = (const float*)d_in[12];
  const float* vb3 = (const float*)d_in[13];
  const float* lw  = (const float*)d_in[14];
  const float* lb  = (const float*)d_in[15];
  float* out = (float*)d_out;

  ncde_kernel<<<Bb / BT, NT, 0, stream>>>(xs, iw1, ib1, iw2, ib2, iw3, ib3,
                                          vw1, vb1, vw2, vb2, vw3, vb3, lw, lb, out);
}

// Round 12
// 2013.533 us; speedup vs baseline: 2.4006x; 2.4006x over previous
//
#include <hip/hip_runtime.h>
#include <math.h>

namespace {

constexpr int Bb = 1024;
constexpr int Tn = 64;
constexpr int Dn = 8;
constexpr int Hn = 64;
constexpr int Wn = 128;
constexpr int BT = 4;     // batch rows per block
constexpr int NT = 1024;  // 16 waves, 4 waves/SIMD, 1 block/CU
constexpr int W1S = 68;   // w1s row stride
constexpr int W2S = 132;  // w2s row stride
constexpr int YS  = 72;   // y/ys row stride: rows 8 banks apart
constexpr int HS  = 136;  // h1/h2 row stride; halves at phys 0 / 68 (gap)
constexpr int GAP = 68;   // phys offset of k=64..127 half
constexpr int KS  = 68;   // K_l inner stride

typedef float v2f __attribute__((ext_vector_type(2)));

// Tsit5 tableau
constexpr float A21 = 0.161f;
constexpr float A31 = -0.008480655492356989f, A32 = 0.335480655492357f;
constexpr float A41 = 2.8971530571054935f, A42 = -6.359448489975075f, A43 = 4.3622954328695815f;
constexpr float A51 = 5.325864828439257f, A52 = -11.748883564062828f, A53 = 7.4955393428898365f, A54 = -0.09249506636175525f;
constexpr float A61 = 5.86145544294642f, A62 = -12.92096931784711f, A63 = 8.159367898576159f, A64 = -0.071584973281401f, A65 = -0.028269050394068383f;
constexpr float Bc1 = 0.09646076681806523f, Bc2 = 0.01f, Bc3 = 0.4798896504144996f;
constexpr float Bc4 = 1.379008574103742f, Bc5 = -3.290069515436081f, Bc6 = 2.324710524099774f;

// fast transcendentals (v_exp/v_log/v_rcp based)
__device__ inline float fast_softplus(float x) {
  const float e = __expf(-fabsf(x));           // e in (0,1]
  return fmaxf(x, 0.f) + __logf(1.f + e);      // 1+e in [1,2]
}
__device__ inline float fast_tanh(float x) {
  const float xc = fminf(fmaxf(x, -10.f), 10.f);
  const float e2 = __expf(2.f * xc);
  return 1.f - __fdividef(2.f, e2 + 1.f);
}
__device__ inline float fast_sigmoid(float z) {
  return __fdividef(1.f, 1.f + __expf(-z));
}
__device__ inline float dot4(float4 w, float4 a) {
  return w.x * a.x + w.y * a.y + w.z * a.z + w.w * a.w;
}
// packed dual-FMA accumulate (v_pk_fma_f32): both operand pairs contiguous
__device__ inline v2f pkfma(v2f a, v2f b, v2f acc) {
  return __builtin_elementwise_fma(a, b, acc);
}

} // namespace

// Persistent per-batch-tile NeuralCDE integrator, 1024 threads/block.
//
// R12 = R9 (2043us, zero-conflict, no-spill) with exactly ONE change:
// L3's dot regrouped into contiguous k-PAIRS so v_pk_fma_f32 applies with
// no splats and no layout change. R10/R11's spills came from consumption
// patterns that broke w3r's AGPR residency (flat 64-read loop / per-element
// splat + dual base pointers). Here w3r is read as aligned v2f pairs --
// the same contiguous-tuple pattern R9's float4 reads proved AGPR-safe:
//   A_b += pk_fma({w3r[4c],w3r[4c+1]}, {h2[kk],h2[kk+1]}, A_b)
// 256 scalar FMA -> 128 pk_fma per thread per stage. Everything else
// (h2_l gap layout, 64 b128 reads, L1/L2 scalar on tid<512, fused update,
// 3 barriers/stage) is R9 VERBATIM.
// Tripwire: FETCH_SIZE >= 1e5 KB => spill returned => revert to R9.
__global__ __launch_bounds__(NT, 4)
void ncde_kernel(const float* __restrict__ xs,
                 const float* __restrict__ iw1, const float* __restrict__ ib1,
                 const float* __restrict__ iw2, const float* __restrict__ ib2,
                 const float* __restrict__ iw3, const float* __restrict__ ib3,
                 const float* __restrict__ vw1, const float* __restrict__ vb1,
                 const float* __restrict__ vw2, const float* __restrict__ vb2,
                 const float* __restrict__ vw3, const float* __restrict__ vb3,
                 const float* __restrict__ lw,  const float* __restrict__ lb,
                 float* __restrict__ out)
{
  __shared__ float w1s[Wn][W1S];          // 34.8 KB: w1s[o][k] row-major
  __shared__ float w2s[Wn][W2S];          // 67.6 KB: w2s[o][k] row-major
  __shared__ float xs_l[BT][Tn * Dn];     // 8 KB control path
  __shared__ float y_l[BT][YS];           // current state
  __shared__ float ys_l[BT][YS];          // stage input
  __shared__ float K_l[6][BT][KS];        // stage slopes
  __shared__ float h1_l[BT][HS];          // gap layout: [0..63] + [68..131]
  __shared__ float h2_l[BT][HS];
  __shared__ float lw_l[Hn];

  const int tid = threadIdx.x;
  const int b12 = tid & 3;          // L1/L2 batch row (tid<512)
  const int oL  = (tid >> 2) & 127; // L1/L2 output neuron (tid<512)
  const int pOL = oL + (oL >= 64 ? 4 : 0);  // gap-mapped phys index
  const int hf  = tid & 1;          // L3 k-half
  const int d   = (tid >> 1) & 7;   // L3 data-dim (vw3 row = tid>>1 = h3*8+d)
  const int h3  = tid >> 4;         // L3 hidden index, 0..63
  const int b0  = blockIdx.x * BT;

  const float b1r = vb1[oL];
  const float b2r = vb2[oL];
  const float b3r = vb3[tid >> 1];
  const float lb0 = lb[0];

  // ---- w3 half-row -> registers, ONCE (contiguous 256B per lane) ----
  float w3r[64];
  {
    const float4* p = (const float4*)(vw3 + tid * 64);  // (tid>>1)*128+(tid&1)*64
    #pragma unroll
    for (int i = 0; i < 16; ++i) {
      float4 v = p[i];
      w3r[4*i+0] = v.x; w3r[4*i+1] = v.y; w3r[4*i+2] = v.z; w3r[4*i+3] = v.w;
    }
  }

  // ---- stage w1/w2 row-major into LDS ----
  #pragma unroll
  for (int i = 0; i < 8; ++i) {           // 8192 f32 / 1024 threads
    const int e = i * NT + tid;           // e = o*64 + k
    w1s[e >> 6][e & 63] = vw1[e];
  }
  #pragma unroll
  for (int i = 0; i < 16; ++i) {          // 16384 f32 / 1024 threads
    const int e = i * NT + tid;           // e = o*128 + k
    w2s[e >> 7][e & 127] = vw2[e];
  }
  // ---- this block's xs rows (512 x float4 = 8 KB) ----
  if (tid < 512)
    ((float4*)&xs_l[0][0])[tid] = ((const float4*)(xs + b0 * Tn * Dn))[tid];
  if (tid < Hn) lw_l[tid] = lw[tid];
  __syncthreads();

  // ---- initial MLP (relu, relu, identity): y0 = mlp(xs[:,0]) ----
  if (tid < 512) {
    const int b = tid >> 7, oo = tid & 127;
    float acc = ib1[oo];
    #pragma unroll
    for (int k = 0; k < Dn; ++k) acc += iw1[oo * Dn + k] * xs_l[b][k];
    h1_l[b][oo + (oo >= 64 ? 4 : 0)] = fmaxf(acc, 0.f);
  }
  __syncthreads();
  if (tid < 512) {
    const int b = tid >> 7, oo = tid & 127;
    float acc = ib2[oo];
    const float4* wrow = (const float4*)(iw2 + oo * Wn);
    #pragma unroll
    for (int k4 = 0; k4 < 16; ++k4)
      acc += dot4(wrow[k4], *(const float4*)&h1_l[b][k4 * 4]);
    #pragma unroll
    for (int k4 = 0; k4 < 16; ++k4)
      acc += dot4(wrow[16 + k4], *(const float4*)&h1_l[b][GAP + k4 * 4]);
    h2_l[b][oo + (oo >= 64 ? 4 : 0)] = fmaxf(acc, 0.f);
  }
  __syncthreads();
  if (tid < BT * Hn) {
    const int b = tid >> 6, h = tid & (Hn - 1);
    float acc = ib3[h];
    const float4* wrow = (const float4*)(iw3 + h * Wn);
    #pragma unroll
    for (int k4 = 0; k4 < 16; ++k4)
      acc += dot4(wrow[k4], *(const float4*)&h2_l[b][k4 * 4]);
    #pragma unroll
    for (int k4 = 0; k4 < 16; ++k4)
      acc += dot4(wrow[16 + k4], *(const float4*)&h2_l[b][GAP + k4 * 4]);
    y_l[b][h]  = acc;
    ys_l[b][h] = acc;
  }
  __syncthreads();

  auto readout = [&](int t) {
    if (tid < BT * Hn) {
      const int wv = tid >> 6, h = tid & (Hn - 1);
      float p = lw_l[h] * y_l[wv][h];
      #pragma unroll
      for (int off = 32; off > 0; off >>= 1) p += __shfl_xor(p, off, 64);
      if (h == 0) out[(b0 + wv) * Tn + t] = fast_sigmoid(p + lb0);
    }
  };
  readout(0);

  // ---- 63 Tsit5 steps; per stage: L1 -> bar -> L2 -> bar -> L3+update -> bar
  #pragma unroll 1
  for (int t = 0; t < Tn - 1; ++t) {
    float dxr[BT];

    #pragma unroll 1
    for (int s = 0; s < 6; ++s) {
      if (s == 0) {
        #pragma unroll
        for (int b = 0; b < BT; ++b)
          dxr[b] = xs_l[b][(t + 1) * Dn + d] - xs_l[b][t * Dn + d];
      }

      // ---- vf layer 1 (tid<512): full 64-k dot, gap-mapped write ----
      if (tid < 512) {
        float acc = b1r;
        #pragma unroll
        for (int k4 = 0; k4 < 16; ++k4)
          acc += dot4(*(const float4*)&w1s[oL][k4 * 4],
                      *(const float4*)&ys_l[b12][k4 * 4]);
        h1_l[b12][pOL] = fast_softplus(acc);
      }
      __syncthreads();
      // ---- vf layer 2 (tid<512): full 128-k dot (front + gapped back) ----
      if (tid < 512) {
        float acc = b2r;
        #pragma unroll
        for (int k4 = 0; k4 < 16; ++k4)
          acc += dot4(*(const float4*)&w2s[oL][k4 * 4],
                      *(const float4*)&h1_l[b12][k4 * 4]);
        #pragma unroll
        for (int k4 = 0; k4 < 16; ++k4)
          acc += dot4(*(const float4*)&w2s[oL][64 + k4 * 4],
                      *(const float4*)&h1_l[b12][GAP + k4 * 4]);
        h2_l[b12][pOL] = fast_softplus(acc);
      }
      __syncthreads();
      // ---- vf layer 3 (all 1024): contiguous-pair pk_fma, fused update ----
      {
        v2f A0 = {0.f, 0.f}, A1 = {0.f, 0.f}, A2 = {0.f, 0.f}, A3 = {0.f, 0.f};
        const int kb = hf ? GAP : 0;      // disjoint bank-quads across hf
        #pragma unroll
        for (int c = 0; c < 16; ++c) {
          const int kk = kb + 4 * c;
          const v2f w01 = *(const v2f*)&w3r[4 * c];      // contiguous pair
          const v2f w23 = *(const v2f*)&w3r[4 * c + 2];  // contiguous pair
          {
            const float4 av = *(const float4*)&h2_l[0][kk];
            const v2f* ap = (const v2f*)&av;
            A0 = pkfma(w01, ap[0], A0);
            A0 = pkfma(w23, ap[1], A0);
          }
          {
            const float4 av = *(const float4*)&h2_l[1][kk];
            const v2f* ap = (const v2f*)&av;
            A1 = pkfma(w01, ap[0], A1);
            A1 = pkfma(w23, ap[1], A1);
          }
          {
            const float4 av = *(const float4*)&h2_l[2][kk];
            const v2f* ap = (const v2f*)&av;
            A2 = pkfma(w01, ap[0], A2);
            A2 = pkfma(w23, ap[1], A2);
          }
          {
            const float4 av = *(const float4*)&h2_l[3][kk];
            const v2f* ap = (const v2f*)&av;
            A3 = pkfma(w01, ap[0], A3);
            A3 = pkfma(w23, ap[1], A3);
          }
        }
        float a0 = A0.x + A0.y, a1 = A1.x + A1.y;
        float a2 = A2.x + A2.y, a3 = A3.x + A3.y;
        // join k-halves (pair lane), tanh, einsum over d
        a0 += __shfl_xor(a0, 1, 64);
        a1 += __shfl_xor(a1, 1, 64);
        a2 += __shfl_xor(a2, 1, 64);
        a3 += __shfl_xor(a3, 1, 64);
        float p0 = fast_tanh(a0 + b3r) * dxr[0];
        float p1 = fast_tanh(a1 + b3r) * dxr[1];
        float p2 = fast_tanh(a2 + b3r) * dxr[2];
        float p3 = fast_tanh(a3 + b3r) * dxr[3];
        p0 += __shfl_xor(p0, 2, 64); p0 += __shfl_xor(p0, 4, 64); p0 += __shfl_xor(p0, 8, 64);
        p1 += __shfl_xor(p1, 2, 64); p1 += __shfl_xor(p1, 4, 64); p1 += __shfl_xor(p1, 8, 64);
        p2 += __shfl_xor(p2, 2, 64); p2 += __shfl_xor(p2, 4, 64); p2 += __shfl_xor(p2, 8, 64);
        p3 += __shfl_xor(p3, 2, 64); p3 += __shfl_xor(p3, 4, 64); p3 += __shfl_xor(p3, 8, 64);
        const int wl = tid & 15;
        if (wl < BT) {
          const float kv = (wl == 0) ? p0 : (wl == 1) ? p1 : (wl == 2) ? p2 : p3;
          K_l[s][wl][h3] = kv;
          float v = y_l[wl][h3];
          if (s == 0)      v += A21 * kv;
          else if (s == 1) v += A31 * K_l[0][wl][h3] + A32 * kv;
          else if (s == 2) v += A41 * K_l[0][wl][h3] + A42 * K_l[1][wl][h3] + A43 * kv;
          else if (s == 3) v += A51 * K_l[0][wl][h3] + A52 * K_l[1][wl][h3]
                              + A53 * K_l[2][wl][h3] + A54 * kv;
          else if (s == 4) v += A61 * K_l[0][wl][h3] + A62 * K_l[1][wl][h3]
                              + A63 * K_l[2][wl][h3] + A64 * K_l[3][wl][h3] + A65 * kv;
          else             v += Bc1 * K_l[0][wl][h3] + Bc2 * K_l[1][wl][h3]
                              + Bc3 * K_l[2][wl][h3] + Bc4 * K_l[3][wl][h3]
                              + Bc5 * K_l[4][wl][h3] + Bc6 * kv;
          if (s < 5) {
            ys_l[wl][h3] = v;
          } else {
            y_l[wl][h3]  = v;
            ys_l[wl][h3] = v;
          }
        }
      }
      __syncthreads();
    }
    readout(t + 1);
  }
}

extern "C" void kernel_launch(void* const* d_in, const int* in_sizes, int n_in,
                              void* d_out, int out_size, void* d_ws, size_t ws_size,
                              hipStream_t stream) {
  const float* xs  = (const float*)d_in[1];
  const float* iw1 = (const float*)d_in[2];
  const float* ib1 = (const float*)d_in[3];
  const float* iw2 = (const float*)d_in[4];
  const float* ib2 = (const float*)d_in[5];
  const float* iw3 = (const float*)d_in[6];
  const float* ib3 = (const float*)d_in[7];
  const float* vw1 = (const float*)d_in[8];
  const float* vb1 = (const float*)d_in[9];
  const float* vw2 = (const float*)d_in[10];
  const float* vb2 = (const float*)d_in[11];
  const float* vw3 = (const float*)d_in[12];
  const float* vb3 = (const float*)d_in[13];
  const float* lw  = (const float*)d_in[14];
  const float* lb  = (const float*)d_in[15];
  float* out = (float*)d_out;

  ncde_kernel<<<Bb / BT, NT, 0, stream>>>(xs, iw1, ib1, iw2, ib2, iw3, ib3,
                                          vw1, vb1, vw2, vb2, vw3, vb3, lw, lb, out);
}

// Round 13
// 1694.494 us; speedup vs baseline: 2.8526x; 1.1883x over previous
//
#include <hip/hip_runtime.h>
#include <math.h>

namespace {

constexpr int Bb = 1024;
constexpr int Tn = 64;
constexpr int Dn = 8;
constexpr int Hn = 64;
constexpr int Wn = 128;
constexpr int BT = 4;     // batch rows per block
constexpr int NT = 1024;  // 16 waves, 4 waves/SIMD, 1 block/CU
constexpr int W1S = 68;   // w1s row stride
constexpr int W2S = 132;  // w2s row stride
constexpr int YS  = 72;   // y/ys row stride: rows 8 banks apart
constexpr int HS2 = 140;  // h1/h2 row stride, quarter-gap layout:
                          // quarter q (32 floats) at phys 36*q; 140%32=12
constexpr int KS  = 68;   // K_l inner stride

typedef float v2f __attribute__((ext_vector_type(2)));

// Tsit5 tableau
constexpr float A21 = 0.161f;
constexpr float A31 = -0.008480655492356989f, A32 = 0.335480655492357f;
constexpr float A41 = 2.8971530571054935f, A42 = -6.359448489975075f, A43 = 4.3622954328695815f;
constexpr float A51 = 5.325864828439257f, A52 = -11.748883564062828f, A53 = 7.4955393428898365f, A54 = -0.09249506636175525f;
constexpr float A61 = 5.86145544294642f, A62 = -12.92096931784711f, A63 = 8.159367898576159f, A64 = -0.071584973281401f, A65 = -0.028269050394068383f;
constexpr float Bc1 = 0.09646076681806523f, Bc2 = 0.01f, Bc3 = 0.4798896504144996f;
constexpr float Bc4 = 1.379008574103742f, Bc5 = -3.290069515436081f, Bc6 = 2.324710524099774f;

// fast transcendentals
__device__ inline float fast_softplus(float x) {
  const float e = __expf(-fabsf(x));
  return fmaxf(x, 0.f) + __logf(1.f + e);
}
__device__ inline float fast_tanh(float x) {
  const float xc = fminf(fmaxf(x, -10.f), 10.f);
  const float e2 = __expf(2.f * xc);
  return 1.f - __fdividef(2.f, e2 + 1.f);
}
__device__ inline float fast_sigmoid(float z) {
  return __fdividef(1.f, 1.f + __expf(-z));
}
__device__ inline float dot4(float4 w, float4 a) {
  return w.x * a.x + w.y * a.y + w.z * a.z + w.w * a.w;
}
__device__ inline v2f pkfma(v2f a, v2f b, v2f acc) {
  return __builtin_elementwise_fma(a, b, acc);
}
__device__ inline int P(int k) { return k + 4 * (k >> 5); }  // quarter-gap map

} // namespace

// Persistent per-batch-tile NeuralCDE integrator, 1024 threads/block.
//
// R13 vs R12 (2013us, VALU 52%, LDS pipe ~57%, conflicts 0): VALU was not
// binding (R12 halved FMAs, time unchanged). Dominant reducible cost =
// L3 LDS traffic (1KB/thread/stage, no row reuse). Changes:
//  1. L3: 2 ROWS/THREAD, k-split 4-way (g2 = tid&3 owns quarter g2*32).
//     Each h2 read feeds BOTH rows -> 32 b128/thread (was 64). Same 64
//     w3 regs (w3r[0..31] row 2rp, [32..63] row 2rp+1, contiguous-pair
//     pk_fma consumption = R12's proven AGPR-safe pattern). k-join via
//     value-retaining butterfly (6 shfl): lane ends with 2 full sums of
//     the SAME batch bl = 2*(g2&1)+((g2>>1)&1), rows 2rp/2rp+1 ->
//     2 tanh, tA+tB partial over d-pair, xor4+xor8 completes einsum.
//  2. h1/h2 quarter-gap layout (P(k), stride 140): quarters land on bank
//     quads {0,4,8,12}; all read/write patterns audited <=2-way (free).
//  3. L1/L2 on ALL 1024 threads (hf1 = tid&1 k-halves + 1 shfl join):
//     same LDS totals, phase critical paths halve, no idle waves.
// Tripwire: FETCH_SIZE >= 1e5 KB => spill => revert to R12.
__global__ __launch_bounds__(NT, 4)
void ncde_kernel(const float* __restrict__ xs,
                 const float* __restrict__ iw1, const float* __restrict__ ib1,
                 const float* __restrict__ iw2, const float* __restrict__ ib2,
                 const float* __restrict__ iw3, const float* __restrict__ ib3,
                 const float* __restrict__ vw1, const float* __restrict__ vb1,
                 const float* __restrict__ vw2, const float* __restrict__ vb2,
                 const float* __restrict__ vw3, const float* __restrict__ vb3,
                 const float* __restrict__ lw,  const float* __restrict__ lb,
                 float* __restrict__ out)
{
  __shared__ float w1s[Wn][W1S];          // 34.8 KB
  __shared__ float w2s[Wn][W2S];          // 67.6 KB
  __shared__ float xs_l[BT][Tn * Dn];     // 8 KB
  __shared__ float y_l[BT][YS];
  __shared__ float ys_l[BT][YS];
  __shared__ float K_l[6][BT][KS];
  __shared__ float h1_l[BT][HS2];         // quarter-gap layout
  __shared__ float h2_l[BT][HS2];
  __shared__ float lw_l[Hn];

  const int tid = threadIdx.x;
  // L1/L2 mapping: all 1024 threads
  const int hf1 = tid & 1;          // k-half
  const int bL  = (tid >> 1) & 3;   // batch row
  const int oA  = tid >> 3;         // output neuron 0..127
  // L3 mapping: 2 rows/thread, quarter k-split
  const int g2  = tid & 3;          // k-quarter
  const int rp  = tid >> 2;         // row-pair id 0..255 (rows 2rp, 2rp+1)
  const int h3  = tid >> 4;         // hidden index 0..63
  const int bl  = 2 * (g2 & 1) + ((g2 >> 1) & 1);  // my batch after butterfly
  const int dA  = 2 * (rp & 3);     // my rows' data-dims: dA, dA+1
  const int b0  = blockIdx.x * BT;

  const float b1r = vb1[oA];
  const float b2r = vb2[oA];
  const float b3A = vb3[2 * rp];
  const float b3B = vb3[2 * rp + 1];
  const float lb0 = lb[0];

  // ---- w3 chunks -> registers, ONCE: rows 2rp/2rp+1, quarter g2 ----
  float w3r[64];
  {
    const float4* pA = (const float4*)(vw3 + (2 * rp) * Wn + g2 * 32);
    const float4* pB = (const float4*)(vw3 + (2 * rp + 1) * Wn + g2 * 32);
    #pragma unroll
    for (int i = 0; i < 8; ++i) {
      float4 v = pA[i];
      w3r[4*i+0] = v.x; w3r[4*i+1] = v.y; w3r[4*i+2] = v.z; w3r[4*i+3] = v.w;
    }
    #pragma unroll
    for (int i = 0; i < 8; ++i) {
      float4 v = pB[i];
      w3r[32+4*i+0] = v.x; w3r[32+4*i+1] = v.y; w3r[32+4*i+2] = v.z; w3r[32+4*i+3] = v.w;
    }
  }

  // ---- stage w1/w2 row-major into LDS ----
  #pragma unroll
  for (int i = 0; i < 8; ++i) {
    const int e = i * NT + tid;           // e = o*64 + k
    w1s[e >> 6][e & 63] = vw1[e];
  }
  #pragma unroll
  for (int i = 0; i < 16; ++i) {
    const int e = i * NT + tid;           // e = o*128 + k
    w2s[e >> 7][e & 127] = vw2[e];
  }
  if (tid < 512)
    ((float4*)&xs_l[0][0])[tid] = ((const float4*)(xs + b0 * Tn * Dn))[tid];
  if (tid < Hn) lw_l[tid] = lw[tid];
  __syncthreads();

  // ---- initial MLP (relu, relu, identity): y0 = mlp(xs[:,0]) ----
  if (tid < 512) {
    const int b = tid >> 7, oo = tid & 127;
    float acc = ib1[oo];
    #pragma unroll
    for (int k = 0; k < Dn; ++k) acc += iw1[oo * Dn + k] * xs_l[b][k];
    h1_l[b][P(oo)] = fmaxf(acc, 0.f);
  }
  __syncthreads();
  if (tid < 512) {
    const int b = tid >> 7, oo = tid & 127;
    float acc = ib2[oo];
    #pragma unroll
    for (int q = 0; q < 4; ++q) {
      const float4* wr = (const float4*)(iw2 + oo * Wn + q * 32);
      #pragma unroll
      for (int j = 0; j < 8; ++j)
        acc += dot4(wr[j], *(const float4*)&h1_l[b][q * 36 + 4 * j]);
    }
    h2_l[b][P(oo)] = fmaxf(acc, 0.f);
  }
  __syncthreads();
  if (tid < BT * Hn) {
    const int b = tid >> 6, h = tid & (Hn - 1);
    float acc = ib3[h];
    #pragma unroll
    for (int q = 0; q < 4; ++q) {
      const float4* wr = (const float4*)(iw3 + h * Wn + q * 32);
      #pragma unroll
      for (int j = 0; j < 8; ++j)
        acc += dot4(wr[j], *(const float4*)&h2_l[b][q * 36 + 4 * j]);
    }
    y_l[b][h]  = acc;
    ys_l[b][h] = acc;
  }
  __syncthreads();

  auto readout = [&](int t) {
    if (tid < BT * Hn) {
      const int wv = tid >> 6, h = tid & (Hn - 1);
      float p = lw_l[h] * y_l[wv][h];
      #pragma unroll
      for (int off = 32; off > 0; off >>= 1) p += __shfl_xor(p, off, 64);
      if (h == 0) out[(b0 + wv) * Tn + t] = fast_sigmoid(p + lb0);
    }
  };
  readout(0);

  // ---- 63 Tsit5 steps; per stage: L1 -> bar -> L2 -> bar -> L3+update -> bar
  #pragma unroll 1
  for (int t = 0; t < Tn - 1; ++t) {
    float dxA, dxB;

    #pragma unroll 1
    for (int s = 0; s < 6; ++s) {
      if (s == 0) {
        dxA = xs_l[bl][(t + 1) * Dn + dA]     - xs_l[bl][t * Dn + dA];
        dxB = xs_l[bl][(t + 1) * Dn + dA + 1] - xs_l[bl][t * Dn + dA + 1];
      }

      // ---- vf layer 1 (all threads): half-k dot + 1-shfl join ----
      {
        const int kb = hf1 * 32;
        v2f acc = {0.f, 0.f};
        #pragma unroll
        for (int c = 0; c < 8; ++c) {
          const float4 wv4 = *(const float4*)&w1s[oA][kb + 4 * c];
          const float4 av4 = *(const float4*)&ys_l[bL][kb + 4 * c];
          const v2f* wp = (const v2f*)&wv4;
          const v2f* ap = (const v2f*)&av4;
          acc = pkfma(wp[0], ap[0], acc);
          acc = pkfma(wp[1], ap[1], acc);
        }
        float a = acc.x + acc.y;
        a += __shfl_xor(a, 1, 64);
        if (hf1 == 0) h1_l[bL][P(oA)] = fast_softplus(a + b1r);
      }
      __syncthreads();
      // ---- vf layer 2 (all threads): half-k dot over gapped h1 ----
      {
        const int wb = 64 * hf1;        // w2 col base
        const int hb = 72 * hf1;        // phys base (quarters 2hf,2hf+1)
        v2f acc = {0.f, 0.f};
        #pragma unroll
        for (int c = 0; c < 8; ++c) {
          const float4 wv4 = *(const float4*)&w2s[oA][wb + 4 * c];
          const float4 av4 = *(const float4*)&h1_l[bL][hb + 4 * c];
          const v2f* wp = (const v2f*)&wv4;
          const v2f* ap = (const v2f*)&av4;
          acc = pkfma(wp[0], ap[0], acc);
          acc = pkfma(wp[1], ap[1], acc);
        }
        #pragma unroll
        for (int c = 0; c < 8; ++c) {
          const float4 wv4 = *(const float4*)&w2s[oA][wb + 32 + 4 * c];
          const float4 av4 = *(const float4*)&h1_l[bL][hb + 36 + 4 * c];
          const v2f* wp = (const v2f*)&wv4;
          const v2f* ap = (const v2f*)&av4;
          acc = pkfma(wp[0], ap[0], acc);
          acc = pkfma(wp[1], ap[1], acc);
        }
        float a = acc.x + acc.y;
        a += __shfl_xor(a, 1, 64);
        if (hf1 == 0) h2_l[bL][P(oA)] = fast_softplus(a + b2r);
      }
      __syncthreads();
      // ---- vf layer 3: 2 rows/thread, quarter k, butterfly reduce ----
      {
        v2f P2[2][4];
        #pragma unroll
        for (int r = 0; r < 2; ++r)
          #pragma unroll
          for (int b = 0; b < BT; ++b) P2[r][b] = (v2f){0.f, 0.f};
        const int hb3 = 36 * g2;        // phys base of quarter g2
        #pragma unroll
        for (int c = 0; c < 8; ++c) {
          const float4 a0 = *(const float4*)&h2_l[0][hb3 + 4 * c];
          const float4 a1 = *(const float4*)&h2_l[1][hb3 + 4 * c];
          const float4 a2 = *(const float4*)&h2_l[2][hb3 + 4 * c];
          const float4 a3 = *(const float4*)&h2_l[3][hb3 + 4 * c];
          #pragma unroll
          for (int r = 0; r < 2; ++r) {
            const v2f w01 = *(const v2f*)&w3r[r * 32 + 4 * c];
            const v2f w23 = *(const v2f*)&w3r[r * 32 + 4 * c + 2];
            const v2f* p0 = (const v2f*)&a0;
            const v2f* p1 = (const v2f*)&a1;
            const v2f* p2 = (const v2f*)&a2;
            const v2f* p3 = (const v2f*)&a3;
            P2[r][0] = pkfma(w01, p0[0], P2[r][0]);
            P2[r][0] = pkfma(w23, p0[1], P2[r][0]);
            P2[r][1] = pkfma(w01, p1[0], P2[r][1]);
            P2[r][1] = pkfma(w23, p1[1], P2[r][1]);
            P2[r][2] = pkfma(w01, p2[0], P2[r][2]);
            P2[r][2] = pkfma(w23, p2[1], P2[r][2]);
            P2[r][3] = pkfma(w01, p3[0], P2[r][3]);
            P2[r][3] = pkfma(w23, p3[1], P2[r][3]);
          }
        }
        float p8[2][4];
        #pragma unroll
        for (int r = 0; r < 2; ++r)
          #pragma unroll
          for (int b = 0; b < BT; ++b) p8[r][b] = P2[r][b].x + P2[r][b].y;

        // butterfly step 1 (xor 1): merge over g2 bit0, keep b-pair
        float q4[2][2];
        #pragma unroll
        for (int r = 0; r < 2; ++r)
          #pragma unroll
          for (int j = 0; j < 2; ++j) {
            const float send = (g2 & 1) ? p8[r][j] : p8[r][2 + j];
            const float recv = __shfl_xor(send, 1, 64);
            q4[r][j] = ((g2 & 1) ? p8[r][2 + j] : p8[r][j]) + recv;
          }
        // butterfly step 2 (xor 2): merge over g2 bit1, keep one b
        float f2[2];
        #pragma unroll
        for (int r = 0; r < 2; ++r) {
          const float send = ((g2 >> 1) & 1) ? q4[r][0] : q4[r][1];
          const float recv = __shfl_xor(send, 2, 64);
          f2[r] = (((g2 >> 1) & 1) ? q4[r][1] : q4[r][0]) + recv;
        }
        // tanh + partial einsum over my d-pair, then complete over d
        const float tA = fast_tanh(f2[0] + b3A) * dxA;
        const float tB = fast_tanh(f2[1] + b3B) * dxB;
        float sp = tA + tB;
        sp += __shfl_xor(sp, 4, 64);
        sp += __shfl_xor(sp, 8, 64);
        // writer + fused tableau update: one lane per (bl, h3)
        if (((tid >> 2) & 3) == 0) {
          K_l[s][bl][h3] = sp;
          float v = y_l[bl][h3];
          if (s == 0)      v += A21 * sp;
          else if (s == 1) v += A31 * K_l[0][bl][h3] + A32 * sp;
          else if (s == 2) v += A41 * K_l[0][bl][h3] + A42 * K_l[1][bl][h3] + A43 * sp;
          else if (s == 3) v += A51 * K_l[0][bl][h3] + A52 * K_l[1][bl][h3]
                              + A53 * K_l[2][bl][h3] + A54 * sp;
          else if (s == 4) v += A61 * K_l[0][bl][h3] + A62 * K_l[1][bl][h3]
                              + A63 * K_l[2][bl][h3] + A64 * K_l[3][bl][h3] + A65 * sp;
          else             v += Bc1 * K_l[0][bl][h3] + Bc2 * K_l[1][bl][h3]
                              + Bc3 * K_l[2][bl][h3] + Bc4 * K_l[3][bl][h3]
                              + Bc5 * K_l[4][bl][h3] + Bc6 * sp;
          if (s < 5) {
            ys_l[bl][h3] = v;
          } else {
            y_l[bl][h3]  = v;
            ys_l[bl][h3] = v;
          }
        }
      }
      __syncthreads();
    }
    readout(t + 1);
  }
}

extern "C" void kernel_launch(void* const* d_in, const int* in_sizes, int n_in,
                              void* d_out, int out_size, void* d_ws, size_t ws_size,
                              hipStream_t stream) {
  const float* xs  = (const float*)d_in[1];
  const float* iw1 = (const float*)d_in[2];
  const float* ib1 = (const float*)d_in[3];
  const float* iw2 = (const float*)d_in[4];
  const float* ib2 = (const float*)d_in[5];
  const float* iw3 = (const float*)d_in[6];
  const float* ib3 = (const float*)d_in[7];
  const float* vw1 = (const float*)d_in[8];
  const float* vb1 = (const float*)d_in[9];
  const float* vw2 = (const float*)d_in[10];
  const float* vb2 = (const float*)d_in[11];
  const float* vw3 = (const float*)d_in[12];
  const float* vb3 = (const float*)d_in[13];
  const float* lw  = (const float*)d_in[14];
  const float* lb  = (const float*)d_in[15];
  float* out = (float*)d_out;

  ncde_kernel<<<Bb / BT, NT, 0, stream>>>(xs, iw1, ib1, iw2, ib2, iw3, ib3,
                                          vw1, vb1, vw2, vb2, vw3, vb3, lw, lb, out);
}